// Round 16
// baseline (3297.895 us; speedup 1.0000x reference)
//
#include <hip/hip_runtime.h>
#include <hip/hip_bf16.h>
#include <hip/hip_fp16.h>
#include <cstdint>

// Problem constants
constexpr int kB = 512;      // batch
constexpr int kT = 80;       // encoder seq len
constexpr int kC = 512;      // in_channels
constexpr int kH = 256;      // hidden
constexpr int kV = 6625;     // classes
constexpr int kGIN = kC + kV; // 7137, gru_wih leading dim

typedef __attribute__((ext_vector_type(8))) short short8;
typedef __attribute__((ext_vector_type(4))) float floatx4;
typedef _Float16 h2v __attribute__((ext_vector_type(2)));
typedef _Float16 half8 __attribute__((ext_vector_type(8)));

__device__ __forceinline__ float fast_tanh(float x) {
  float e = __expf(2.f * x);
  return 1.f - 2.f / (e + 1.f);
}
__device__ __forceinline__ float fast_sig(float x) {
  return 1.f / (1.f + __expf(-x));
}
__device__ __forceinline__ float2 h2f(unsigned int u) {
  union { unsigned int u; __half2 h; } cvt; cvt.u = u;
  return __half22float2(cvt.h);
}
__device__ __forceinline__ h2v as_h2v(unsigned int u) {
  union { unsigned int u; h2v h; } c; c.u = u; return c.h;
}
// fused fp16-pair dot with fp32 accumulate: a.x*b.x + a.y*b.y + c
__device__ __forceinline__ float fdot2f(unsigned int a, unsigned int b, float c) {
#if __has_builtin(__builtin_amdgcn_fdot2)
  return __builtin_amdgcn_fdot2(as_h2v(a), as_h2v(b), c, false);
#else
  h2v av = as_h2v(a), bv = as_h2v(b);
  return (float)av[0] * (float)bv[0] + (float)av[1] * (float)bv[1] + c;
#endif
}

__device__ __forceinline__ void gld_lds16(const void* g, void* l) {
  __builtin_amdgcn_global_load_lds(
      (const __attribute__((address_space(1))) void*)(uintptr_t)g,
      (__attribute__((address_space(3))) void*)(uintptr_t)l, 16, 0, 0);
}

// ---------------------------------------------------------------------------
// fp32 -> bf16 conversion (gen_w)
// ---------------------------------------------------------------------------
__global__ __launch_bounds__(256) void cvt_bf16(const float* __restrict__ x,
                                                __hip_bfloat16* __restrict__ y,
                                                int n) {
  int i = blockIdx.x * 256 + threadIdx.x;
  if (i < n) y[i] = __float2bfloat16(x[i]);
}

// ---------------------------------------------------------------------------
// fp32 -> fp16 conversion, 4 elems/thread (inputs -> inH, i2h_w -> i2hH)
// ---------------------------------------------------------------------------
__global__ __launch_bounds__(256) void cvt_fp16x4(const float* __restrict__ x,
                                                  __half* __restrict__ y) {
  int i = (blockIdx.x * 256 + threadIdx.x) * 4;
  float4 v = *(const float4*)(x + i);
  __half2 h01 = __floats2half2_rn(v.x, v.y);
  __half2 h23 = __floats2half2_rn(v.z, v.w);
  uint2 u;
  u.x = *reinterpret_cast<unsigned int*>(&h01);
  u.y = *reinterpret_cast<unsigned int*>(&h23);
  *(uint2*)(y + i) = u;
}

// ---------------------------------------------------------------------------
// One-time: wH[n][c] fp16, n<1024: rows 0..255 = h2h_w, 256..1023 = gru_whh
// ---------------------------------------------------------------------------
__global__ __launch_bounds__(256) void cvt_wh(const float* __restrict__ h2h,
                                              const float* __restrict__ whh,
                                              __half* __restrict__ wH) {
  const int n = blockIdx.x, c = threadIdx.x;
  float v = (n < kH) ? h2h[(size_t)n * kH + c] : whh[(size_t)(n - kH) * kH + c];
  wH[(size_t)n * kH + c] = __float2half(v);
}

// ---------------------------------------------------------------------------
// One-time: wihH[n][c] fp16 = wih[n][c] for n<768, c<512 (aligned, packed).
// ---------------------------------------------------------------------------
__global__ __launch_bounds__(256) void cvt_wih(const float* __restrict__ wih,
                                               __half* __restrict__ wihH) {
  const int n = blockIdx.x, t = threadIdx.x;
  wihH[(size_t)n * kC + t] = __float2half(wih[(size_t)n * kGIN + t]);
  wihH[(size_t)n * kC + 256 + t] = __float2half(wih[(size_t)n * kGIN + 256 + t]);
}

// ---------------------------------------------------------------------------
// One-time transpose with bias fold: WT[v][n] = wih[n][kC+v] + bih[n]  (fp32)
// ---------------------------------------------------------------------------
__global__ __launch_bounds__(256) void wt_transpose(const float* __restrict__ wih,
                                                    const float* __restrict__ bih,
                                                    float* __restrict__ WT) {
  __shared__ float tile[32][33];
  const int vb = blockIdx.x * 32, nb = blockIdx.y * 32;
  const int tx = threadIdx.x & 31, ty0 = threadIdx.x >> 5;  // 32 x 8
#pragma unroll
  for (int i = 0; i < 4; ++i) {
    int n = nb + ty0 + i * 8;
    int v = vb + tx;
    tile[ty0 + i * 8][tx] = (v < kV) ? wih[(size_t)n * kGIN + kC + v] : 0.f;
  }
  __syncthreads();
  const float bb = bih[nb + tx];
#pragma unroll
  for (int i = 0; i < 4; ++i) {
    int v = vb + ty0 + i * 8;
    if (v < kV) WT[(size_t)v * 768 + nb + tx] = tile[tx][ty0 + i * 8] + bb;
  }
}

// ---------------------------------------------------------------------------
// proj GEMM, fp16 MFMA: projH[M,N] = inH[M,K] * i2hH[N,K]^T, fp16 out.
// M=40960, N=256 (2 tiles, exact), K=512. Same skeleton as final_gemm.
// ---------------------------------------------------------------------------
__global__ __launch_bounds__(256) void proj_gemm_f16(
    const __half* __restrict__ A, const __half* __restrict__ W,
    __half* __restrict__ C) {
  constexpr int K = kC, ldc = kH;
  __shared__ __align__(16) _Float16 As[128 * 32];
  __shared__ __align__(16) _Float16 Ws[128 * 32];
  const int tid = threadIdx.x;
  const int wave = tid >> 6, lane = tid & 63;
  const int m0 = blockIdx.x * 128, n0 = blockIdx.y * 128;
  floatx4 acc[4][4] = {};
  const int lr = lane & 15;
  const int lkb = (lane >> 4) * 8;
  const int mloc = (wave & 1) * 64;
  const int nloc = (wave >> 1) * 64;
  const int srow = wave * 16 + (lane >> 2);
  const int skq = (lane & 3) * 8;
  for (int kt = 0; kt < K; kt += 32) {
#pragma unroll
    for (int r = 0; r < 2; ++r) {
      int rowA = r * 64 + srow;
      const __half* ga = A + (size_t)(m0 + rowA) * K + kt + skq;
      gld_lds16(ga, (char*)As + (size_t)(r * 64 + wave * 16) * 64);
      const __half* gw = W + (size_t)(n0 + rowA) * K + kt + skq;
      gld_lds16(gw, (char*)Ws + (size_t)(r * 64 + wave * 16) * 64);
    }
    __syncthreads();
    half8 af[4], wf[4];
#pragma unroll
    for (int i = 0; i < 4; ++i)
      af[i] = *(const half8*)(As + (mloc + i * 16 + lr) * 32 + lkb);
#pragma unroll
    for (int j = 0; j < 4; ++j)
      wf[j] = *(const half8*)(Ws + (nloc + j * 16 + lr) * 32 + lkb);
#pragma unroll
    for (int i = 0; i < 4; ++i)
#pragma unroll
      for (int j = 0; j < 4; ++j)
        acc[i][j] = __builtin_amdgcn_mfma_f32_16x16x32_f16(af[i], wf[j], acc[i][j], 0, 0, 0);
    __syncthreads();
  }
#pragma unroll
  for (int i = 0; i < 4; ++i) {
#pragma unroll
    for (int j = 0; j < 4; ++j) {
      int col = n0 + nloc + j * 16 + lr;
      int rowb = m0 + mloc + i * 16 + ((lane >> 4) << 2);
#pragma unroll
      for (int r = 0; r < 4; ++r)
        C[(size_t)(rowb + r) * ldc + col] = __float2half(acc[i][j][r]);
    }
  }
}

// gh chunk: waves 4..7 (32 groups) compute 8 rows each of gh = hidh @ whh^T,
// overlapped with the attention phases on waves 0..3.
#define GH_CHUNK(cidx)                                                        \
  {                                                                           \
    const int g2 = (tid >> 3) - 32;                                           \
    for (int j = 0; j < 8; ++j) {                                             \
      int jj = (cidx) * 8 + j + rot24; if (jj >= 24) jj -= 24;                \
      const int m = g2 + (jj << 5);                                           \
      const _Float16* wr = wH + (size_t)(256 + m) * kH;                       \
      float a0 = 0.f;                                                         \
      _Pragma("unroll")                                                       \
      for (int p = 0; p < 4; ++p) {                                           \
        const int c = p * 64 + q * 8;                                         \
        uint4 wv = *(const uint4*)(wr + c);                                   \
        uint4 hv = *(const uint4*)(&hidh_s[c]);                               \
        a0 = fdot2f(wv.x, hv.x, a0);                                          \
        a0 = fdot2f(wv.y, hv.y, a0);                                          \
        a0 = fdot2f(wv.z, hv.z, a0);                                          \
        a0 = fdot2f(wv.w, hv.w, a0);                                          \
      }                                                                       \
      a0 += __shfl_xor(a0, 1); a0 += __shfl_xor(a0, 2); a0 += __shfl_xor(a0, 4); \
      if (q == 0) phgh_s[256 + m] = a0 + bhh[m];                              \
    }                                                                         \
  }

// ---------------------------------------------------------------------------
// Persistent fused recurrence v11: 512 blocks x 512 threads, 1 row/block.
// WAVE SPECIALIZATION: gh (768 rows, consumed only in phase 4) runs on waves
// 4-7 concurrently with the attention phases (2a/2b/2c on waves 0-3) -- gh's
// L2-load latency hides under attention's transcendental VALU work (separate
// pipes co-schedule, m114). Phase 3 = gi only. Barriers 7 -> 6.
// Occupancy note: allocator offers only {64+spill, ~116..}-VGPR configs for
// this shape (rounds 14/15); we stay in the 1-block/CU regime and optimize
// within it.
// ---------------------------------------------------------------------------
__global__ __launch_bounds__(512, 2) void fused_steps(
    const __half* __restrict__ inH,      // [B,T,C] fp16
    const __half* __restrict__ projH,    // [B*T,H] fp16
    const int*   __restrict__ targets,   // [B,S]
    const __half* __restrict__ wHp,      // [1024,256] fp16 [h2h; whh]
    const float* __restrict__ h2h_b, const float* __restrict__ bhh,
    const __half* __restrict__ wihHp,    // [768,512] fp16
    const float* __restrict__ WT,        // [V,768] fp32 (bih folded)
    const float* __restrict__ score_w,
    __hip_bfloat16* __restrict__ hidd,   // [B*S,H]
    int S) {
  __shared__ __align__(16) float hid_s[kH];        // 1 KB   fp32 GRU state
  __shared__ __align__(16) _Float16 hidh_s[kH];    // 512 B  fp16 shadow
  __shared__ __align__(16) float phgh_s[1024];     // 4 KB   [ph | gh]
  __shared__ __align__(16) _Float16 ctxh_s[kC];    // 1 KB   fp16 context
  __shared__ __align__(16) float gi_s[768];        // 3 KB
  __shared__ float e_s[kT];                        // 320 B
  const int tid = threadIdx.x;
  const int bid = blockIdx.x;
  const int r0 = bid;                            // this block's batch row
  const int wave = tid >> 6, lane = tid & 63;    // 8 waves
  const int g = tid >> 3, q = tid & 7;           // 64 groups of 8 threads
  const _Float16* wH = (const _Float16*)wHp;
  const _Float16* wihH = (const _Float16*)wihHp;

  if (tid < kH) { hid_s[tid] = 0.f; hidh_s[tid] = (_Float16)0.f; }

  // score_w slice for this lane (fixed per thread) -> 4 regs
  const float4 s4 = *(const float4*)(score_w + lane * 4);

  // ---- waves 0-3 preload this row's proj slice as fp16 (uint2 pr[20]).
  // Task mapping matches phase 2a: t = wave + 4*k, h-slice = lane*4.
  uint2 pr[20];
  if (wave < 4) {
#pragma unroll
    for (int k = 0; k < 20; ++k) {
      const int t = wave + 4 * k;
      pr[k] = *(const uint2*)(projH + ((size_t)r0 * kT + t) * kH + lane * 4);
    }
  }
  __syncthreads();

  const int rot = bid % 12;    // gi rotation
  const int rot24 = bid % 24;  // gh rotation

  for (int s = 0; s < S; ++s) {
    // ---- phase 1: ph[0:256] = h @ h2h^T + b (all waves, 4 rows/group)
#pragma unroll
    for (int i = 0; i < 4; ++i) {
      const int n = g + (((i + bid) & 3) << 6);
      const _Float16* wr = wH + (size_t)n * kH;
      float a0 = 0.f;
#pragma unroll
      for (int p = 0; p < 4; ++p) {
        const int c = p * 64 + q * 8;
        uint4 wv = *(const uint4*)(wr + c);
        uint4 hv = *(const uint4*)(&hidh_s[c]);
        a0 = fdot2f(wv.x, hv.x, a0);
        a0 = fdot2f(wv.y, hv.y, a0);
        a0 = fdot2f(wv.z, hv.z, a0);
        a0 = fdot2f(wv.w, hv.w, a0);
      }
      a0 += __shfl_xor(a0, 1); a0 += __shfl_xor(a0, 2); a0 += __shfl_xor(a0, 4);
      if (q == 0) phgh_s[n] = a0 + h2h_b[n];
    }
    __syncthreads();  // B1

    // ---- region 1: waves 0-3 phase 2a | waves 4-7 gh chunk 0
    if (wave < 4) {
      float4 ph4 = *(const float4*)(&phgh_s[lane * 4]);
#pragma unroll
      for (int k = 0; k < 20; ++k) {
        const int t = wave + 4 * k;
        float2 p01 = h2f(pr[k].x), p23 = h2f(pr[k].y);
        float part = fast_tanh(p01.x + ph4.x) * s4.x +
                     fast_tanh(p01.y + ph4.y) * s4.y +
                     fast_tanh(p23.x + ph4.z) * s4.z +
                     fast_tanh(p23.y + ph4.w) * s4.w;
#pragma unroll
        for (int off = 32; off > 0; off >>= 1) part += __shfl_xor(part, off);
        if (lane == 0) e_s[t] = part;
      }
    } else GH_CHUNK(0)
    __syncthreads();  // B2

    // ---- region 2: wave 0 softmax | waves 4-7 gh chunk 1
    if (wave == 0) {
      float v0 = e_s[lane];
      float v1 = (lane < kT - 64) ? e_s[64 + lane] : -1e30f;
      float mx = fmaxf(v0, v1);
#pragma unroll
      for (int off = 32; off > 0; off >>= 1) mx = fmaxf(mx, __shfl_xor(mx, off));
      float x0 = __expf(v0 - mx);
      float x1 = (lane < kT - 64) ? __expf(v1 - mx) : 0.f;
      float sm = x0 + x1;
#pragma unroll
      for (int off = 32; off > 0; off >>= 1) sm += __shfl_xor(sm, off);
      float inv = 1.f / sm;
      e_s[lane] = x0 * inv;
      if (lane < kT - 64) e_s[64 + lane] = x1 * inv;
    } else if (wave >= 4) GH_CHUNK(1)
    __syncthreads();  // B3

    // ---- region 3: waves 0-3 phase 2c | waves 4-7 gh chunk 2
    if (wave < 4) {
      const int c2 = tid * 2;  // tid < 256 covers 512 cols
      const __half* ib = inH + (size_t)r0 * kT * kC + c2;
      float a0 = 0.f, a1 = 0.f;
#pragma unroll 4
      for (int t = 0; t < kT; ++t) {
        const float al = e_s[t];
        float2 v = h2f(*(const unsigned int*)(ib + (size_t)t * kC));
        a0 += al * v.x; a1 += al * v.y;
      }
      ctxh_s[c2] = (_Float16)a0;
      ctxh_s[c2 + 1] = (_Float16)a1;
    } else GH_CHUNK(2)
    __syncthreads();  // B4

    // ---- phase 3: gi[n] = ctxh @ wihH[n,:]  (all waves, 12 rows/group)
#pragma unroll 2
    for (int i = 0; i < 12; ++i) {
      int io = i + rot; if (io >= 12) io -= 12;
      const int n = g + (io << 6);
      const _Float16* wr = wihH + (size_t)n * kC;
      float a0 = 0.f, b0 = 0.f;
#pragma unroll
      for (int p = 0; p < 8; p += 2) {
        const int c0 = p * 64 + q * 8;
        const int c1 = c0 + 64;
        uint4 wv0 = *(const uint4*)(wr + c0);
        uint4 wv1 = *(const uint4*)(wr + c1);
        uint4 xv0 = *(const uint4*)(&ctxh_s[c0]);
        uint4 xv1 = *(const uint4*)(&ctxh_s[c1]);
        a0 = fdot2f(wv0.x, xv0.x, a0);
        a0 = fdot2f(wv0.y, xv0.y, a0);
        a0 = fdot2f(wv0.z, xv0.z, a0);
        a0 = fdot2f(wv0.w, xv0.w, a0);
        b0 = fdot2f(wv1.x, xv1.x, b0);
        b0 = fdot2f(wv1.y, xv1.y, b0);
        b0 = fdot2f(wv1.z, xv1.z, b0);
        b0 = fdot2f(wv1.w, xv1.w, b0);
      }
      a0 += b0;
      a0 += __shfl_xor(a0, 1); a0 += __shfl_xor(a0, 2); a0 += __shfl_xor(a0, 4);
      if (q == 0) gi_s[n] = a0;
    }
    __syncthreads();  // B5

    // ---- phase 4: GRU update (256 threads = 256 h)
    if (tid < kH) {
      const int h = tid;
      const int tg = targets[(size_t)r0 * S + s];
      const float* wtr = WT + (size_t)tg * 768;
      float i_r = gi_s[h] + wtr[h];
      float i_z = gi_s[kH + h] + wtr[kH + h];
      float i_n = gi_s[2 * kH + h] + wtr[2 * kH + h];
      float h_r = phgh_s[kH + h];
      float h_z = phgh_s[2 * kH + h];
      float h_n = phgh_s[3 * kH + h];
      float hv = hid_s[h];
      float rr = fast_sig(i_r + h_r);
      float z = fast_sig(i_z + h_z);
      float nn = fast_tanh(i_n + rr * h_n);
      float o = (1.f - z) * nn + z * hv;
      hid_s[h] = o;
      hidh_s[h] = (_Float16)o;
      hidd[((size_t)r0 * S + s) * kH + h] = __float2bfloat16(o);
    }
    __syncthreads();  // B6
  }
}

// ---------------------------------------------------------------------------
// Final GEMM, bf16 MFMA: C[M,N] = A[M,K] * W[N,K]^T + bias[n]
// 128x128 tile, BK=32, 4 waves in 2x2, 16x16x32 mfma, global_load_lds x16.
// 1D grid (5200 = 100 M-tiles x 52 N-tiles) with bijective XCD swizzle.
// ---------------------------------------------------------------------------
__global__ __launch_bounds__(256) void final_gemm(
    const __hip_bfloat16* __restrict__ A, const __hip_bfloat16* __restrict__ W,
    const float* __restrict__ bias, float* __restrict__ C, int M, int N, int K) {
  __shared__ __align__(16) short As[128 * 32];
  __shared__ __align__(16) short Ws[128 * 32];
  const int tid = threadIdx.x;
  const int wave = tid >> 6, lane = tid & 63;
  const int u = blockIdx.x;                    // 5200 blocks
  const int idx = (u & 7) * 650 + (u >> 3);    // XCD-contiguous remap
  const int m0 = (idx % 100) * 128, n0 = (idx / 100) * 128;
  floatx4 acc[4][4] = {};
  const int lr = lane & 15;
  const int lkb = (lane >> 4) * 8;
  const int mloc = (wave & 1) * 64;
  const int nloc = (wave >> 1) * 64;
  const int srow = wave * 16 + (lane >> 2);
  const int skq = (lane & 3) * 8;
  for (int kt = 0; kt < K; kt += 32) {
#pragma unroll
    for (int r = 0; r < 2; ++r) {
      int rowA = r * 64 + srow;
      const __hip_bfloat16* ga = A + (size_t)(m0 + rowA) * K + kt + skq;
      gld_lds16(ga, (char*)As + (size_t)(r * 64 + wave * 16) * 64);
      int rowW = n0 + rowA;
      if (rowW > N - 1) rowW = N - 1;
      const __hip_bfloat16* gw = W + (size_t)rowW * K + kt + skq;
      gld_lds16(gw, (char*)Ws + (size_t)(r * 64 + wave * 16) * 64);
    }
    __syncthreads();
    short8 af[4], wf[4];
#pragma unroll
    for (int i = 0; i < 4; ++i)
      af[i] = *(const short8*)(As + (mloc + i * 16 + lr) * 32 + lkb);
#pragma unroll
    for (int j = 0; j < 4; ++j)
      wf[j] = *(const short8*)(Ws + (nloc + j * 16 + lr) * 32 + lkb);
#pragma unroll
    for (int i = 0; i < 4; ++i)
#pragma unroll
      for (int j = 0; j < 4; ++j)
        acc[i][j] = __builtin_amdgcn_mfma_f32_16x16x32_bf16(af[i], wf[j], acc[i][j], 0, 0, 0);
    __syncthreads();
  }
#pragma unroll
  for (int i = 0; i < 4; ++i) {
#pragma unroll
    for (int j = 0; j < 4; ++j) {
      int col = n0 + nloc + j * 16 + lr;
      if (col < N) {
        int rowb = m0 + mloc + i * 16 + ((lane >> 4) << 2);
        float bs = bias[col];
#pragma unroll
        for (int r = 0; r < 4; ++r)
          C[(size_t)(rowb + r) * N + col] = acc[i][j][r] + bs;
      }
    }
  }
}

// ---------------------------------------------------------------------------
extern "C" void kernel_launch(void* const* d_in, const int* in_sizes, int n_in,
                              void* d_out, int out_size, void* d_ws, size_t ws_size,
                              hipStream_t stream) {
  const float* inputs  = (const float*)d_in[0];
  const int*   targets = (const int*)d_in[1];
  // d_in[2] = batch_max_length (device scalar); S derived from out_size instead
  const float* i2h_w   = (const float*)d_in[3];
  const float* h2h_w   = (const float*)d_in[4];
  const float* h2h_b   = (const float*)d_in[5];
  const float* score_w = (const float*)d_in[6];
  const float* gru_wih = (const float*)d_in[7];
  const float* gru_whh = (const float*)d_in[8];
  const float* gru_bih = (const float*)d_in[9];
  const float* gru_bhh = (const float*)d_in[10];
  const float* gen_w   = (const float*)d_in[11];
  const float* gen_b   = (const float*)d_in[12];
  float* out = (float*)d_out;
  const int S = out_size / (kB * kV);  // 25

  // workspace carve (~95 MB)
  char* ws = (char*)d_ws;
  size_t off = 0;
  auto alloc = [&](size_t bytes) {
    void* p = ws + off;
    off += (bytes + 255) & ~(size_t)255;
    return p;
  };
  __half* projH = (__half*)alloc((size_t)kB * kT * kH * 2); // 21 MB
  float* WT   = (float*)alloc((size_t)kV * 768 * 4);        // 20.4 MB
  __half* inH = (__half*)alloc((size_t)kB * kT * kC * 2);   // 41.9 MB
  __half* wH  = (__half*)alloc((size_t)1024 * kH * 2);      // 0.5 MB
  __half* wihH = (__half*)alloc((size_t)768 * kC * 2);      // 0.75 MB
  __half* i2hH = (__half*)alloc((size_t)kH * kC * 2);       // 0.25 MB
  __hip_bfloat16* hidd = (__hip_bfloat16*)alloc((size_t)kB * S * kH * 2);
  __hip_bfloat16* gw16 = (__hip_bfloat16*)alloc((size_t)kV * kH * 2);

  cvt_bf16<<<dim3((kV * kH + 255) / 256), 256, 0, stream>>>(gen_w, gw16, kV * kH);
  cvt_fp16x4<<<dim3(kB * kT * kC / 4 / 256), 256, 0, stream>>>(inputs, inH);
  cvt_fp16x4<<<dim3(kH * kC / 4 / 256), 256, 0, stream>>>(i2h_w, i2hH);
  cvt_wh<<<dim3(1024), 256, 0, stream>>>(h2h_w, gru_whh, wH);
  cvt_wih<<<dim3(768), 256, 0, stream>>>(gru_wih, wihH);
  wt_transpose<<<dim3((kV + 31) / 32, 768 / 32), 256, 0, stream>>>(gru_wih, gru_bih, WT);

  // projH = inH @ i2hH^T   [B*T, H], K=C  (fp16 MFMA, fp16 out)
  proj_gemm_f16<<<dim3(kB * kT / 128, kH / 128), 256, 0, stream>>>(inH, i2hH, projH);

  // the entire 25-step recurrence: one persistent kernel, 1 row/block;
  // gh wave-specialized under the attention phases
  fused_steps<<<dim3(kB), 512, 0, stream>>>(
      inH, projH, targets, wH, h2h_b, gru_bhh, wihH, WT, score_w, hidd, S);

  // probs = hidd @ gen_w^T + gen_b   [B*S, V], K=H (bf16 MFMA, XCD-swizzled)
  final_gemm<<<dim3(100 * 52), 256, 0, stream>>>(
      hidd, gw16, gen_b, out, kB * S, kV, kH);
}

// Round 17
// 1550.257 us; speedup vs baseline: 2.1273x; 2.1273x over previous
//
#include <hip/hip_runtime.h>
#include <hip/hip_bf16.h>
#include <hip/hip_fp16.h>
#include <cstdint>

// Problem constants
constexpr int kB = 512;      // batch
constexpr int kT = 80;       // encoder seq len
constexpr int kC = 512;      // in_channels
constexpr int kH = 256;      // hidden
constexpr int kV = 6625;     // classes
constexpr int kGIN = kC + kV; // 7137, gru_wih leading dim

typedef __attribute__((ext_vector_type(8))) short short8;
typedef __attribute__((ext_vector_type(4))) float floatx4;
typedef _Float16 h2v __attribute__((ext_vector_type(2)));
typedef _Float16 half8 __attribute__((ext_vector_type(8)));

__device__ __forceinline__ float fast_tanh(float x) {
  float e = __expf(2.f * x);
  return 1.f - 2.f / (e + 1.f);
}
__device__ __forceinline__ float fast_sig(float x) {
  return 1.f / (1.f + __expf(-x));
}
__device__ __forceinline__ float2 h2f(unsigned int u) {
  union { unsigned int u; __half2 h; } cvt; cvt.u = u;
  return __half22float2(cvt.h);
}
__device__ __forceinline__ h2v as_h2v(unsigned int u) {
  union { unsigned int u; h2v h; } c; c.u = u; return c.h;
}
// fused fp16-pair dot with fp32 accumulate: a.x*b.x + a.y*b.y + c
__device__ __forceinline__ float fdot2f(unsigned int a, unsigned int b, float c) {
#if __has_builtin(__builtin_amdgcn_fdot2)
  return __builtin_amdgcn_fdot2(as_h2v(a), as_h2v(b), c, false);
#else
  h2v av = as_h2v(a), bv = as_h2v(b);
  return (float)av[0] * (float)bv[0] + (float)av[1] * (float)bv[1] + c;
#endif
}

__device__ __forceinline__ void gld_lds16(const void* g, void* l) {
  __builtin_amdgcn_global_load_lds(
      (const __attribute__((address_space(1))) void*)(uintptr_t)g,
      (__attribute__((address_space(3))) void*)(uintptr_t)l, 16, 0, 0);
}

// ---------------------------------------------------------------------------
// fp32 -> bf16 conversion (gen_w)
// ---------------------------------------------------------------------------
__global__ __launch_bounds__(256) void cvt_bf16(const float* __restrict__ x,
                                                __hip_bfloat16* __restrict__ y,
                                                int n) {
  int i = blockIdx.x * 256 + threadIdx.x;
  if (i < n) y[i] = __float2bfloat16(x[i]);
}

// ---------------------------------------------------------------------------
// fp32 -> fp16 conversion, 4 elems/thread (inputs -> inH, i2h_w -> i2hH)
// ---------------------------------------------------------------------------
__global__ __launch_bounds__(256) void cvt_fp16x4(const float* __restrict__ x,
                                                  __half* __restrict__ y) {
  int i = (blockIdx.x * 256 + threadIdx.x) * 4;
  float4 v = *(const float4*)(x + i);
  __half2 h01 = __floats2half2_rn(v.x, v.y);
  __half2 h23 = __floats2half2_rn(v.z, v.w);
  uint2 u;
  u.x = *reinterpret_cast<unsigned int*>(&h01);
  u.y = *reinterpret_cast<unsigned int*>(&h23);
  *(uint2*)(y + i) = u;
}

// ---------------------------------------------------------------------------
// One-time: wH[n][c] fp16, n<1024: rows 0..255 = h2h_w, 256..1023 = gru_whh
// ---------------------------------------------------------------------------
__global__ __launch_bounds__(256) void cvt_wh(const float* __restrict__ h2h,
                                              const float* __restrict__ whh,
                                              __half* __restrict__ wH) {
  const int n = blockIdx.x, c = threadIdx.x;
  float v = (n < kH) ? h2h[(size_t)n * kH + c] : whh[(size_t)(n - kH) * kH + c];
  wH[(size_t)n * kH + c] = __float2half(v);
}

// ---------------------------------------------------------------------------
// One-time: wihH[n][c] fp16 = wih[n][c] for n<768, c<512 (aligned, packed).
// ---------------------------------------------------------------------------
__global__ __launch_bounds__(256) void cvt_wih(const float* __restrict__ wih,
                                               __half* __restrict__ wihH) {
  const int n = blockIdx.x, t = threadIdx.x;
  wihH[(size_t)n * kC + t] = __float2half(wih[(size_t)n * kGIN + t]);
  wihH[(size_t)n * kC + 256 + t] = __float2half(wih[(size_t)n * kGIN + 256 + t]);
}

// ---------------------------------------------------------------------------
// One-time transpose with bias fold: WT[v][n] = wih[n][kC+v] + bih[n]  (fp32)
// ---------------------------------------------------------------------------
__global__ __launch_bounds__(256) void wt_transpose(const float* __restrict__ wih,
                                                    const float* __restrict__ bih,
                                                    float* __restrict__ WT) {
  __shared__ float tile[32][33];
  const int vb = blockIdx.x * 32, nb = blockIdx.y * 32;
  const int tx = threadIdx.x & 31, ty0 = threadIdx.x >> 5;  // 32 x 8
#pragma unroll
  for (int i = 0; i < 4; ++i) {
    int n = nb + ty0 + i * 8;
    int v = vb + tx;
    tile[ty0 + i * 8][tx] = (v < kV) ? wih[(size_t)n * kGIN + kC + v] : 0.f;
  }
  __syncthreads();
  const float bb = bih[nb + tx];
#pragma unroll
  for (int i = 0; i < 4; ++i) {
    int v = vb + ty0 + i * 8;
    if (v < kV) WT[(size_t)v * 768 + nb + tx] = tile[tx][ty0 + i * 8] + bb;
  }
}

// ---------------------------------------------------------------------------
// proj GEMM, fp16 MFMA: projH[M,N] = inH[M,K] * i2hH[N,K]^T, fp16 out.
// M=40960, N=256 (2 tiles, exact), K=512. Same skeleton as final_gemm.
// ---------------------------------------------------------------------------
__global__ __launch_bounds__(256) void proj_gemm_f16(
    const __half* __restrict__ A, const __half* __restrict__ W,
    __half* __restrict__ C) {
  constexpr int K = kC, ldc = kH;
  __shared__ __align__(16) _Float16 As[128 * 32];
  __shared__ __align__(16) _Float16 Ws[128 * 32];
  const int tid = threadIdx.x;
  const int wave = tid >> 6, lane = tid & 63;
  const int m0 = blockIdx.x * 128, n0 = blockIdx.y * 128;
  floatx4 acc[4][4] = {};
  const int lr = lane & 15;
  const int lkb = (lane >> 4) * 8;
  const int mloc = (wave & 1) * 64;
  const int nloc = (wave >> 1) * 64;
  const int srow = wave * 16 + (lane >> 2);
  const int skq = (lane & 3) * 8;
  for (int kt = 0; kt < K; kt += 32) {
#pragma unroll
    for (int r = 0; r < 2; ++r) {
      int rowA = r * 64 + srow;
      const __half* ga = A + (size_t)(m0 + rowA) * K + kt + skq;
      gld_lds16(ga, (char*)As + (size_t)(r * 64 + wave * 16) * 64);
      const __half* gw = W + (size_t)(n0 + rowA) * K + kt + skq;
      gld_lds16(gw, (char*)Ws + (size_t)(r * 64 + wave * 16) * 64);
    }
    __syncthreads();
    half8 af[4], wf[4];
#pragma unroll
    for (int i = 0; i < 4; ++i)
      af[i] = *(const half8*)(As + (mloc + i * 16 + lr) * 32 + lkb);
#pragma unroll
    for (int j = 0; j < 4; ++j)
      wf[j] = *(const half8*)(Ws + (nloc + j * 16 + lr) * 32 + lkb);
#pragma unroll
    for (int i = 0; i < 4; ++i)
#pragma unroll
      for (int j = 0; j < 4; ++j)
        acc[i][j] = __builtin_amdgcn_mfma_f32_16x16x32_f16(af[i], wf[j], acc[i][j], 0, 0, 0);
    __syncthreads();
  }
#pragma unroll
  for (int i = 0; i < 4; ++i) {
#pragma unroll
    for (int j = 0; j < 4; ++j) {
      int col = n0 + nloc + j * 16 + lr;
      int rowb = m0 + mloc + i * 16 + ((lane >> 4) << 2);
#pragma unroll
      for (int r = 0; r < 4; ++r)
        C[(size_t)(rowb + r) * ldc + col] = __float2half(acc[i][j][r]);
    }
  }
}

// ---------------------------------------------------------------------------
// Persistent fused recurrence (round-15 verified best: fused 1068us, total
// 1556us, VGPR 116 spill-free): 512 blocks x 512 threads, 1 row/block.
// fdot2 fused convert+2FMA (fp16 shadows hidh/ctxh, fp32 GRU state);
// phase 1 = ph only (small pre-attention critical path); gh merged into
// phase 3. fp16 proj preload in registers (20 VGPRs).
// Refuted alternatives (kept for the record): 2-row weight amortization
// (r11/r12: spills), (512,4)/waves_per_eu occupancy forcing (r14: pins
// VGPR=64 + 53-700 MB scratch), wave-specialized gh (r16: pressure >128 ->
// pinned 128 + 104 MB spill), cooperative grid-sync (r2: barrier-bound).
// ---------------------------------------------------------------------------
__global__ __launch_bounds__(512, 2) void fused_steps(
    const __half* __restrict__ inH,      // [B,T,C] fp16
    const __half* __restrict__ projH,    // [B*T,H] fp16
    const int*   __restrict__ targets,   // [B,S]
    const __half* __restrict__ wHp,      // [1024,256] fp16 [h2h; whh]
    const float* __restrict__ h2h_b, const float* __restrict__ bhh,
    const __half* __restrict__ wihHp,    // [768,512] fp16
    const float* __restrict__ WT,        // [V,768] fp32 (bih folded)
    const float* __restrict__ score_w,
    __hip_bfloat16* __restrict__ hidd,   // [B*S,H]
    int S) {
  __shared__ __align__(16) float hid_s[kH];        // 1 KB   fp32 GRU state
  __shared__ __align__(16) _Float16 hidh_s[kH];    // 512 B  fp16 shadow
  __shared__ __align__(16) float phgh_s[1024];     // 4 KB   [ph | gh]
  __shared__ __align__(16) _Float16 ctxh_s[kC];    // 1 KB   fp16 context
  __shared__ __align__(16) float cst[kC];          // 2 KB   2c partials
  __shared__ __align__(16) float gi_s[768];        // 3 KB
  __shared__ float e_s[kT];                        // 320 B
  const int tid = threadIdx.x;
  const int bid = blockIdx.x;
  const int r0 = bid;                            // this block's batch row
  const int wave = tid >> 6, lane = tid & 63;    // 8 waves
  const int g = tid >> 3, q = tid & 7;           // 64 groups of 8 threads
  const _Float16* wH = (const _Float16*)wHp;
  const _Float16* wihH = (const _Float16*)wihHp;

  if (tid < kH) { hid_s[tid] = 0.f; hidh_s[tid] = (_Float16)0.f; }

  // score_w slice for this lane (fixed per thread) -> 4 regs
  const float4 s4 = *(const float4*)(score_w + lane * 4);

  // ---- preload the block's proj slice into registers as fp16 (20 VGPRs).
  // Task mapping matches phase 2a: t = wave + 8*k, h-slice = lane*4.
  uint2 pr[10];
#pragma unroll
  for (int k = 0; k < 10; ++k) {
    const int t = wave + 8 * k;
    pr[k] = *(const uint2*)(projH + ((size_t)r0 * kT + t) * kH + lane * 4);
  }
  __syncthreads();

  const int rot = bid % 12;

  for (int s = 0; s < S; ++s) {
    // ---- phase 1: ph[0:256] = h @ h2h^T + b  (ONLY the attention input;
    // gh deferred to phase 3). 64 groups x 4 rows; fdot2 inner loop.
#pragma unroll
    for (int i = 0; i < 4; ++i) {
      const int n = g + (((i + bid) & 3) << 6);
      const _Float16* wr = wH + (size_t)n * kH;
      float a0 = 0.f;
#pragma unroll
      for (int p = 0; p < 4; ++p) {
        const int c = p * 64 + q * 8;
        uint4 wv = *(const uint4*)(wr + c);
        uint4 hv = *(const uint4*)(&hidh_s[c]);
        a0 = fdot2f(wv.x, hv.x, a0);
        a0 = fdot2f(wv.y, hv.y, a0);
        a0 = fdot2f(wv.z, hv.z, a0);
        a0 = fdot2f(wv.w, hv.w, a0);
      }
      a0 += __shfl_xor(a0, 1); a0 += __shfl_xor(a0, 2); a0 += __shfl_xor(a0, 4);
      if (q == 0) phgh_s[n] = a0 + h2h_b[n];
    }
    __syncthreads();

    // ---- phase 2a: e[t] = sum_h tanh(proj[t,h]+ph[h])*sw[h]
    // proj fp16 in registers -> 2 unpacks + pure VALU.
    {
      float4 ph4 = *(const float4*)(&phgh_s[lane * 4]);
#pragma unroll
      for (int k = 0; k < 10; ++k) {
        const int t = wave + 8 * k;
        float2 p01 = h2f(pr[k].x), p23 = h2f(pr[k].y);
        float part = fast_tanh(p01.x + ph4.x) * s4.x +
                     fast_tanh(p01.y + ph4.y) * s4.y +
                     fast_tanh(p23.x + ph4.z) * s4.z +
                     fast_tanh(p23.y + ph4.w) * s4.w;
#pragma unroll
        for (int off = 32; off > 0; off >>= 1) part += __shfl_xor(part, off);
        if (lane == 0) e_s[t] = part;
      }
    }
    __syncthreads();

    // ---- phase 2b: softmax over T=80 (wave 0)
    if (wave == 0) {
      float v0 = e_s[lane];
      float v1 = (lane < kT - 64) ? e_s[64 + lane] : -1e30f;
      float mx = fmaxf(v0, v1);
#pragma unroll
      for (int off = 32; off > 0; off >>= 1) mx = fmaxf(mx, __shfl_xor(mx, off));
      float x0 = __expf(v0 - mx);
      float x1 = (lane < kT - 64) ? __expf(v1 - mx) : 0.f;
      float sm = x0 + x1;
#pragma unroll
      for (int off = 32; off > 0; off >>= 1) sm += __shfl_xor(sm, off);
      float inv = 1.f / sm;
      e_s[lane] = x0 * inv;
      if (lane < kT - 64) e_s[64 + lane] = x1 * inv;
    }
    __syncthreads();

    // ---- phase 2c: ctx[c] = sum_t alpha[t]*inH[t,c]  (fp32 acc, fp16 out)
    {
      const int sub = tid >> 8, c2 = (tid & 255) * 2;
      const __half* ib = inH + (size_t)r0 * kT * kC + c2;
      float a0 = 0.f, a1 = 0.f;
      const int t0 = sub * 40;
#pragma unroll 4
      for (int t = t0; t < t0 + 40; ++t) {
        const float al = e_s[t];
        float2 v = h2f(*(const unsigned int*)(ib + (size_t)t * kC));
        a0 += al * v.x; a1 += al * v.y;
      }
      if (sub) { cst[c2] = a0; cst[c2 + 1] = a1; }
      __syncthreads();
      if (!sub) {
        ctxh_s[c2] = (_Float16)(a0 + cst[c2]);
        ctxh_s[c2 + 1] = (_Float16)(a1 + cst[c2 + 1]);
      }
    }
    __syncthreads();

    // ---- phase 3: gi[n] = ctxh @ wihH[n,:]  AND  gh[m] = hidh @ whh[m,:]
    // (gh consumed only by phase 4 -- merged here off the critical path).
#pragma unroll 2
    for (int i = 0; i < 12; ++i) {
      int io = i + rot; if (io >= 12) io -= 12;
      const int n = g + (io << 6);
      const _Float16* wr = wihH + (size_t)n * kC;
      float a0 = 0.f, b0 = 0.f;
#pragma unroll
      for (int p = 0; p < 8; p += 2) {
        const int c0 = p * 64 + q * 8;
        const int c1 = c0 + 64;
        uint4 wv0 = *(const uint4*)(wr + c0);
        uint4 wv1 = *(const uint4*)(wr + c1);
        uint4 xv0 = *(const uint4*)(&ctxh_s[c0]);
        uint4 xv1 = *(const uint4*)(&ctxh_s[c1]);
        a0 = fdot2f(wv0.x, xv0.x, a0);
        a0 = fdot2f(wv0.y, xv0.y, a0);
        a0 = fdot2f(wv0.z, xv0.z, a0);
        a0 = fdot2f(wv0.w, xv0.w, a0);
        b0 = fdot2f(wv1.x, xv1.x, b0);
        b0 = fdot2f(wv1.y, xv1.y, b0);
        b0 = fdot2f(wv1.z, xv1.z, b0);
        b0 = fdot2f(wv1.w, xv1.w, b0);
      }
      a0 += b0;
      a0 += __shfl_xor(a0, 1); a0 += __shfl_xor(a0, 2); a0 += __shfl_xor(a0, 4);
      if (q == 0) gi_s[n] = a0;
    }
#pragma unroll 2
    for (int i = 0; i < 12; ++i) {
      int io = i + rot; if (io >= 12) io -= 12;
      const int m = g + (io << 6);
      const _Float16* wr = wH + (size_t)(256 + m) * kH;
      float a0 = 0.f;
#pragma unroll
      for (int p = 0; p < 4; ++p) {
        const int c = p * 64 + q * 8;
        uint4 wv = *(const uint4*)(wr + c);
        uint4 hv = *(const uint4*)(&hidh_s[c]);
        a0 = fdot2f(wv.x, hv.x, a0);
        a0 = fdot2f(wv.y, hv.y, a0);
        a0 = fdot2f(wv.z, hv.z, a0);
        a0 = fdot2f(wv.w, hv.w, a0);
      }
      a0 += __shfl_xor(a0, 1); a0 += __shfl_xor(a0, 2); a0 += __shfl_xor(a0, 4);
      if (q == 0) phgh_s[256 + m] = a0 + bhh[m];
    }
    __syncthreads();

    // ---- phase 4: GRU update (256 threads = 256 h)
    if (tid < kH) {
      const int h = tid;
      const int tg = targets[(size_t)r0 * S + s];
      const float* wtr = WT + (size_t)tg * 768;
      float i_r = gi_s[h] + wtr[h];
      float i_z = gi_s[kH + h] + wtr[kH + h];
      float i_n = gi_s[2 * kH + h] + wtr[2 * kH + h];
      float h_r = phgh_s[kH + h];
      float h_z = phgh_s[2 * kH + h];
      float h_n = phgh_s[3 * kH + h];
      float hv = hid_s[h];
      float rr = fast_sig(i_r + h_r);
      float z = fast_sig(i_z + h_z);
      float nn = fast_tanh(i_n + rr * h_n);
      float o = (1.f - z) * nn + z * hv;
      hid_s[h] = o;
      hidh_s[h] = (_Float16)o;
      hidd[((size_t)r0 * S + s) * kH + h] = __float2bfloat16(o);
    }
    __syncthreads();
  }
}

// ---------------------------------------------------------------------------
// Final GEMM, bf16 MFMA: C[M,N] = A[M,K] * W[N,K]^T + bias[n]
// 128x128 tile, BK=32, 4 waves in 2x2, 16x16x32 mfma, global_load_lds x16.
// 1D grid (5200 = 100 M-tiles x 52 N-tiles) with bijective XCD swizzle
// (5200 % 8 == 0): each XCD owns a contiguous chunk -> W-panel L2 locality.
// ---------------------------------------------------------------------------
__global__ __launch_bounds__(256) void final_gemm(
    const __hip_bfloat16* __restrict__ A, const __hip_bfloat16* __restrict__ W,
    const float* __restrict__ bias, float* __restrict__ C, int M, int N, int K) {
  __shared__ __align__(16) short As[128 * 32];
  __shared__ __align__(16) short Ws[128 * 32];
  const int tid = threadIdx.x;
  const int wave = tid >> 6, lane = tid & 63;
  const int u = blockIdx.x;                    // 5200 blocks
  const int idx = (u & 7) * 650 + (u >> 3);    // XCD-contiguous remap
  const int m0 = (idx % 100) * 128, n0 = (idx / 100) * 128;
  floatx4 acc[4][4] = {};
  const int lr = lane & 15;
  const int lkb = (lane >> 4) * 8;
  const int mloc = (wave & 1) * 64;
  const int nloc = (wave >> 1) * 64;
  const int srow = wave * 16 + (lane >> 2);
  const int skq = (lane & 3) * 8;
  for (int kt = 0; kt < K; kt += 32) {
#pragma unroll
    for (int r = 0; r < 2; ++r) {
      int rowA = r * 64 + srow;
      const __hip_bfloat16* ga = A + (size_t)(m0 + rowA) * K + kt + skq;
      gld_lds16(ga, (char*)As + (size_t)(r * 64 + wave * 16) * 64);
      int rowW = n0 + rowA;
      if (rowW > N - 1) rowW = N - 1;
      const __hip_bfloat16* gw = W + (size_t)rowW * K + kt + skq;
      gld_lds16(gw, (char*)Ws + (size_t)(r * 64 + wave * 16) * 64);
    }
    __syncthreads();
    short8 af[4], wf[4];
#pragma unroll
    for (int i = 0; i < 4; ++i)
      af[i] = *(const short8*)(As + (mloc + i * 16 + lr) * 32 + lkb);
#pragma unroll
    for (int j = 0; j < 4; ++j)
      wf[j] = *(const short8*)(Ws + (nloc + j * 16 + lr) * 32 + lkb);
#pragma unroll
    for (int i = 0; i < 4; ++i)
#pragma unroll
      for (int j = 0; j < 4; ++j)
        acc[i][j] = __builtin_amdgcn_mfma_f32_16x16x32_bf16(af[i], wf[j], acc[i][j], 0, 0, 0);
    __syncthreads();
  }
#pragma unroll
  for (int i = 0; i < 4; ++i) {
#pragma unroll
    for (int j = 0; j < 4; ++j) {
      int col = n0 + nloc + j * 16 + lr;
      if (col < N) {
        int rowb = m0 + mloc + i * 16 + ((lane >> 4) << 2);
        float bs = bias[col];
#pragma unroll
        for (int r = 0; r < 4; ++r)
          C[(size_t)(rowb + r) * N + col] = acc[i][j][r] + bs;
      }
    }
  }
}

// ---------------------------------------------------------------------------
extern "C" void kernel_launch(void* const* d_in, const int* in_sizes, int n_in,
                              void* d_out, int out_size, void* d_ws, size_t ws_size,
                              hipStream_t stream) {
  const float* inputs  = (const float*)d_in[0];
  const int*   targets = (const int*)d_in[1];
  // d_in[2] = batch_max_length (device scalar); S derived from out_size instead
  const float* i2h_w   = (const float*)d_in[3];
  const float* h2h_w   = (const float*)d_in[4];
  const float* h2h_b   = (const float*)d_in[5];
  const float* score_w = (const float*)d_in[6];
  const float* gru_wih = (const float*)d_in[7];
  const float* gru_whh = (const float*)d_in[8];
  const float* gru_bih = (const float*)d_in[9];
  const float* gru_bhh = (const float*)d_in[10];
  const float* gen_w   = (const float*)d_in[11];
  const float* gen_b   = (const float*)d_in[12];
  float* out = (float*)d_out;
  const int S = out_size / (kB * kV);  // 25

  // workspace carve (~95 MB)
  char* ws = (char*)d_ws;
  size_t off = 0;
  auto alloc = [&](size_t bytes) {
    void* p = ws + off;
    off += (bytes + 255) & ~(size_t)255;
    return p;
  };
  __half* projH = (__half*)alloc((size_t)kB * kT * kH * 2); // 21 MB
  float* WT   = (float*)alloc((size_t)kV * 768 * 4);        // 20.4 MB
  __half* inH = (__half*)alloc((size_t)kB * kT * kC * 2);   // 41.9 MB
  __half* wH  = (__half*)alloc((size_t)1024 * kH * 2);      // 0.5 MB
  __half* wihH = (__half*)alloc((size_t)768 * kC * 2);      // 0.75 MB
  __half* i2hH = (__half*)alloc((size_t)kH * kC * 2);       // 0.25 MB
  __hip_bfloat16* hidd = (__hip_bfloat16*)alloc((size_t)kB * S * kH * 2);
  __hip_bfloat16* gw16 = (__hip_bfloat16*)alloc((size_t)kV * kH * 2);

  cvt_bf16<<<dim3((kV * kH + 255) / 256), 256, 0, stream>>>(gen_w, gw16, kV * kH);
  cvt_fp16x4<<<dim3(kB * kT * kC / 4 / 256), 256, 0, stream>>>(inputs, inH);
  cvt_fp16x4<<<dim3(kH * kC / 4 / 256), 256, 0, stream>>>(i2h_w, i2hH);
  cvt_wh<<<dim3(1024), 256, 0, stream>>>(h2h_w, gru_whh, wH);
  cvt_wih<<<dim3(768), 256, 0, stream>>>(gru_wih, wihH);
  wt_transpose<<<dim3((kV + 31) / 32, 768 / 32), 256, 0, stream>>>(gru_wih, gru_bih, WT);

  // projH = inH @ i2hH^T   [B*T, H], K=C  (fp16 MFMA, fp16 out)
  proj_gemm_f16<<<dim3(kB * kT / 128, kH / 128), 256, 0, stream>>>(inH, i2hH, projH);

  // the entire 25-step recurrence: one persistent kernel, 1 row/block
  fused_steps<<<dim3(kB), 512, 0, stream>>>(
      inH, projH, targets, wH, h2h_b, gru_bhh, wihH, WT, score_w, hidd, S);

  // probs = hidd @ gen_w^T + gen_b   [B*S, V], K=H (bf16 MFMA, XCD-swizzled)
  final_gemm<<<dim3(100 * 52), 256, 0, stream>>>(
      hidd, gw16, gen_b, out, kB * S, kV, kH);
}